// Round 16
// baseline (151.841 us; speedup 1.0000x reference)
//
#include <hip/hip_runtime.h>
#include <math.h>

#define N_CODES     1024
#define CODE_DIM    64
#define ROWS_TOTAL  131072
#define CAND_CAP    12
#define GMARGIN     1e-3f
#define BROWS       128                      // rows per block (4 waves x 32)
#define STAGE_CODES 128
#define STAGE_BYTES (STAGE_CODES * CODE_DIM * 2)   // 16384

typedef float  f32x16  __attribute__((ext_vector_type(16)));
typedef short  short8v __attribute__((ext_vector_type(8)));
typedef __attribute__((address_space(3))) unsigned       lds_u32;
typedef const __attribute__((address_space(1))) unsigned glb_u32;

// ---------- frozen bit-exact pieces (verified rounds 2-15) ----------
__device__ __forceinline__ float np_sumsq64_s(const float* a, int stride) {
#pragma clang fp contract(off)
    float r[8];
    #pragma unroll
    for (int j = 0; j < 8; ++j) r[j] = a[j * stride] * a[j * stride];
    #pragma unroll
    for (int t = 1; t < 8; ++t) {
        #pragma unroll
        for (int j = 0; j < 8; ++j) {
            const float v = a[(t * 8 + j) * stride];
            const float p = v * v;
            r[j] = r[j] + p;
        }
    }
    return ((r[0] + r[1]) + (r[2] + r[3])) + ((r[4] + r[5]) + (r[6] + r[7]));
}

// same tree, reading element c at rq[c ^ x] (XOR-swizzled LDS row copy)
__device__ __forceinline__ float np_sumsq64_lds(const float* rq, int x) {
#pragma clang fp contract(off)
    float r[8];
    #pragma unroll
    for (int j = 0; j < 8; ++j) { const float v = rq[j ^ x]; r[j] = v * v; }
    #pragma unroll
    for (int t = 1; t < 8; ++t) {
        #pragma unroll
        for (int j = 0; j < 8; ++j) {
            const float v = rq[(t * 8 + j) ^ x];
            const float p = v * v;
            r[j] = r[j] + p;
        }
    }
    return ((r[0] + r[1]) + (r[2] + r[3])) + ((r[4] + r[5]) + (r[6] + r[7]));
}

__device__ __forceinline__ unsigned short bf16rne(float f) {
    unsigned int u = __float_as_uint(f);
    return (unsigned short)((u + 0x7FFFu + ((u >> 16) & 1u)) >> 16);
}

__device__ __forceinline__ f32x16 zero16() {
    f32x16 v;
    #pragma unroll
    for (int e = 0; e < 16; ++e) v[e] = 0.f;
    return v;
}

__device__ __forceinline__ float exact_dot_lds(const float* rq, int x,
                                               const float* __restrict__ cb, int k) {
    const float4* wr = (const float4*)(cb + (size_t)k * CODE_DIM);
    float G = 0.f;
    #pragma unroll
    for (int c4 = 0; c4 < 16; ++c4) {
        const float4 wv = wr[c4];
        G = __builtin_fmaf(rq[(c4 * 4 + 0) ^ x], wv.x, G);
        G = __builtin_fmaf(rq[(c4 * 4 + 1) ^ x], wv.y, G);
        G = __builtin_fmaf(rq[(c4 * 4 + 2) ^ x], wv.z, G);
        G = __builtin_fmaf(rq[(c4 * 4 + 3) ^ x], wv.w, G);
    }
    return G;
}

// ordered (T,k) key: smaller key == (smaller T, then smaller k)
__device__ __forceinline__ unsigned long long packTK(float T, int k) {
    unsigned u = __float_as_uint(T);
    unsigned m = (u & 0x80000000u) ? ~u : (u | 0x80000000u);
    return ((unsigned long long)m << 32) | (unsigned)k;
}

// ========== K0: prep — ||w||^2 (numpy tree) + bf16 pre-swizzled codebook ==========
__global__ __launch_bounds__(512) void vq_prep(const float* __restrict__ cb,
                                               unsigned short* __restrict__ cbbf,
                                               float* __restrict__ Csws) {
    const int sid = blockIdx.x * 512 + threadIdx.x;       // 0..8191 (16B slots)
    const float4* cb4 = (const float4*)cb;
    const float4 f0 = cb4[sid * 2 + 0];
    const float4 f1 = cb4[sid * 2 + 1];
    short8v h;
    h[0] = (short)bf16rne(f0.x); h[1] = (short)bf16rne(f0.y);
    h[2] = (short)bf16rne(f0.z); h[3] = (short)bf16rne(f0.w);
    h[4] = (short)bf16rne(f1.x); h[5] = (short)bf16rne(f1.y);
    h[6] = (short)bf16rne(f1.z); h[7] = (short)bf16rne(f1.w);
    const int code = sid >> 3, c8 = sid & 7;
    const int off = (code >> 7) * STAGE_BYTES +
                    (((code & 127) * 128 + c8 * 16) ^ ((code & 7) << 4));
    *(short8v*)((char*)cbbf + off) = h;
    if (sid < N_CODES) Csws[sid] = np_sumsq64_s(cb + sid * CODE_DIM, 1);
}

// ========== K1: FUSED single-pass top-3 screen + compacted rescore + gather =======
// 256 threads = 4 waves x 32 rows = 128 rows/block; grid 1024; LDS = 40960 (4/CU).
// Single pass: per (lane,e) slot keep sorted top-3 packed (score | code-idx in low
// 10 mantissa bits). Missed-candidate detection: if slot's 3rd >= threshold, a 4th
// could be too -> flag row into the exact coop-full-scan path. Exact: any dropped
// value <= s3, so s3 < th guarantees nothing above th was lost.
__global__ __launch_bounds__(256, 4) void vq_fused(
    const float* __restrict__ vec, const unsigned short* __restrict__ cbbf,
    const float* __restrict__ cb, const float* __restrict__ Csws,
    float* __restrict__ out)
{
    __shared__ __align__(16) char pool[2 * STAGE_BYTES];      // cbuf (screen) / rows (tail)
    __shared__ int cnt[BROWS];                                // cnt (screen) / S (tail)
    __shared__ int ks[BROWS * CAND_CAP];                      // 6 KB
    __shared__ unsigned long long res[BROWS];                 // 1 KB
    __shared__ int taskOff[BROWS];                            // 512 B
    // total: 32768 + 512 + 6144 + 1024 + 512 = 40960

    const int tid = threadIdx.x;
    const int l   = tid & 63;
    const int w   = tid >> 6;          // wave 0..3
    const int col = l & 31;
    const int g8  = l >> 5;
    const int rowblk = blockIdx.x * BROWS;

    // ---- A fragment: this lane's row, bf16, pinned in VGPRs ----
    const int r = rowblk + w * 32 + col;
    const float* xb = vec + (size_t)(r >> 12) * 262144 + (r & 4095);
    short8v a[4];
    #pragma unroll
    for (int m = 0; m < 4; ++m) {
        #pragma unroll
        for (int j = 0; j < 8; ++j) {
            const int c = m * 16 + g8 * 8 + j;
            a[m][j] = (short)bf16rne(xb[(size_t)c * 4096]);
        }
    }
    asm volatile("s_waitcnt vmcnt(0)" ::: "memory");
    #pragma unroll
    for (int m = 0; m < 4; ++m) {
        int4 t; __builtin_memcpy(&t, &a[m], 16);
        asm volatile("" : "+v"(t.x), "+v"(t.y), "+v"(t.z), "+v"(t.w));
        __builtin_memcpy(&a[m], &t, 16);
    }

    if (l < 32) cnt[w * 32 + l] = 0;   // wave-local rows; barriers below order it

    const char* gsrc = (const char*)cbbf;
    #define STAGE(stg, bufi)                                                        \
        do {                                                                        \
            _Pragma("unroll")                                                       \
            for (int i = 0; i < 4; ++i) {                                           \
                const char* g = gsrc + (stg) * STAGE_BYTES + i * 4096 + tid * 16;   \
                lds_u32* lb = (lds_u32*)(pool + (bufi) * STAGE_BYTES + i * 4096 + (w << 10)); \
                __builtin_amdgcn_global_load_lds((glb_u32*)g, lb, 16, 0, 0);        \
            }                                                                       \
        } while (0)

    // sorted per-slot top-3 (packed score|idx), s1 >= s2 >= s3
    f32x16 s1, s2, s3;
    #pragma unroll
    for (int e = 0; e < 16; ++e) { s1[e] = -INFINITY; s2[e] = -INFINITY; s3[e] = -INFINITY; }

    STAGE(0, 0);
    for (int s = 0; s < 8; ++s) {                      // SINGLE pass over 8 stages
        const int cur = s & 1;
        if (s < 7) {
            STAGE(s + 1, cur ^ 1);
            asm volatile("s_waitcnt vmcnt(4)" ::: "memory");
        } else {
            asm volatile("s_waitcnt vmcnt(0)" ::: "memory");
        }
        __builtin_amdgcn_s_barrier();
        __builtin_amdgcn_sched_barrier(0);

        const char* base = pool + cur * STAGE_BYTES;
        const int kbase = s * STAGE_CODES;
        #pragma unroll
        for (int tt = 0; tt < 4; ++tt) {
            const int cl = tt * 32 + col;
            short8v bf[4];
            #pragma unroll
            for (int m = 0; m < 4; ++m) {
                const int off = (cl * 128 + (m * 2 + g8) * 16) ^ ((cl & 7) << 4);
                bf[m] = *(const short8v*)(base + off);
            }
            f32x16 acc = zero16();
            #pragma unroll
            for (int m = 0; m < 4; ++m)
                acc = __builtin_amdgcn_mfma_f32_32x32x16_bf16(a[m], bf[m], acc, 0, 0, 0);

            const unsigned kk = (unsigned)(kbase + cl); // 10 bits
            #pragma unroll
            for (int e = 0; e < 16; ++e) {
                // pack code idx into low 10 mantissa bits (<=1023 ulp ~ 6e-7 perturb)
                const float pv = __uint_as_float((__float_as_uint(acc[e]) & ~1023u) | kk);
                const float n1 = fmaxf(s1[e], pv);
                const float n2 = __builtin_amdgcn_fmed3f(s1[e], s2[e], pv);
                const float n3 = __builtin_amdgcn_fmed3f(s2[e], s3[e], pv);
                s1[e] = n1; s2[e] = n2; s3[e] = n3;
            }
        }
        __builtin_amdgcn_s_barrier();
    }
    #undef STAGE

    // ---- collection: butterfly max -> threshold -> emit top-3 per slot ----
    #pragma unroll
    for (int e = 0; e < 16; ++e) {
        float m = s1[e];
        m = fmaxf(m, __shfl_xor(m, 1, 64));
        m = fmaxf(m, __shfl_xor(m, 2, 64));
        m = fmaxf(m, __shfl_xor(m, 4, 64));
        m = fmaxf(m, __shfl_xor(m, 8, 64));
        m = fmaxf(m, __shfl_xor(m, 16, 64));
        const float th = m - GMARGIN;
        const int rl = w * 32 + (e & 3) + ((e >> 2) << 3) + (g8 << 2);
        if (s1[e] >= th) {
            const int idx = atomicAdd(&cnt[rl], 1);
            if (idx < CAND_CAP) ks[rl * CAND_CAP + idx] = (int)(__float_as_uint(s1[e]) & 1023u);
        }
        if (s2[e] >= th) {
            const int idx = atomicAdd(&cnt[rl], 1);
            if (idx < CAND_CAP) ks[rl * CAND_CAP + idx] = (int)(__float_as_uint(s2[e]) & 1023u);
        }
        if (s3[e] >= th) {
            // slot saturated at threshold: a 4th candidate may have been dropped.
            // Force the exact full-scan path for this row (conservative, exact).
            atomicAdd(&cnt[rl], 64);
        }
    }

    // ================= tail: compacted exact rescore (frozen r10/r13) =============
    __syncthreads();                                   // all waves done with pool

    float (*rows)[CODE_DIM] = (float (*)[CODE_DIM])(pool + (size_t)w * 8192);
    float* Sarr = (float*)cnt;                         // overlay after cnt consumed

    const int c0 = (l < 32) ? cnt[w * 32 + l] : 0;
    if (l < 32) {
        res[w * 32 + l] = ~0ULL;
        if (c0 == 1) res[w * 32 + l] = (unsigned long long)(unsigned)ks[(w * 32 + l) * CAND_CAP];
    }
    const unsigned long long om0 = __ballot(l < 32 && c0 > CAND_CAP);
    int tq = (l < 32 && c0 >= 2 && c0 <= CAND_CAP) ? c0 : 0;

    int scan = tq;
    #pragma unroll
    for (int off = 1; off < 32; off <<= 1) {
        const int v = __shfl_up(scan, off, 64);
        if (l >= off) scan += v;
    }
    if (l < 32) taskOff[w * 32 + l] = scan - tq;
    const int total = __shfl(scan, 31, 64);

    {
        const int q2 = l & 31, hh = l >> 5;
        const int rr = rowblk + w * 32 + q2;
        const float* rb = vec + (size_t)(rr >> 12) * 262144 + (rr & 4095);
        #pragma unroll 4
        for (int i = 0; i < 32; ++i) {
            const int c = i * 2 + hh;
            rows[q2][c ^ q2] = rb[(size_t)c * 4096];
        }
    }
    if (l < 32) Sarr[w * 32 + l] = np_sumsq64_lds(rows[l], l);

    __syncthreads();

    for (int t = l; t < total; t += 64) {
        int lo = 0, hi = 31;
        #pragma unroll
        for (int it = 0; it < 5; ++it) {
            const int mid = (lo + hi + 1) >> 1;
            if (taskOff[w * 32 + mid] <= t) lo = mid; else hi = mid - 1;
        }
        const int q = lo;
        const int k = ks[(w * 32 + q) * CAND_CAP + (t - taskOff[w * 32 + q])];
        const float S = Sarr[w * 32 + q];
        const float G = exact_dot_lds(rows[q], q, cb, k);
        const float T = __builtin_fmaf(-2.f, G, S) + Csws[k];
        atomicMin(&res[w * 32 + q], packTK(T, k));
    }

    unsigned long long om = om0;
    while (om) {
        const int q = (int)__builtin_ctzll(om); om &= om - 1;
        const float S = Sarr[w * 32 + q];
        float bT = INFINITY; int bK = 0x7fffffff;
        #pragma unroll 4
        for (int j = 0; j < 16; ++j) {
            const int k = l * 16 + j;
            const float G = exact_dot_lds(rows[q], q, cb, k);
            const float T = __builtin_fmaf(-2.f, G, S) + Csws[k];
            if (T < bT) { bT = T; bK = k; }
        }
        #pragma unroll
        for (int off = 32; off; off >>= 1) {
            const float oT = __shfl_xor(bT, off, 64);
            const int   oK = __shfl_xor(bK, off, 64);
            if (oT < bT || (oT == bT && oK < bK)) { bT = oT; bK = oK; }
        }
        if (l == 0) res[w * 32 + q] = (unsigned long long)(unsigned)bK;
    }

    __syncthreads();

    const int c4 = (tid & 15) << 2;
    for (int rr = tid >> 4; rr < BROWS; rr += 16) {
        const int wi = (int)(res[rr] & 0xffffffffu);
        const float4 v = *(const float4*)(cb + (size_t)wi * CODE_DIM + c4);
        *(float4*)(out + (size_t)(rowblk + rr) * CODE_DIM + c4) = v;
    }
}

// ================= fallback (round-4 kernel, used if ws too small) =================
#define KTILE 128
#define NTILES (N_CODES / KTILE)
__global__ __launch_bounds__(256, 2) void vq_lds_fallback(
    const float* __restrict__ vec, const float* __restrict__ cb,
    float* __restrict__ out)
{
    __shared__ __align__(16) float sw[2][KTILE * CODE_DIM];
    __shared__ __align__(16) float Cs[N_CODES];
    __shared__ int idxs[256];

    const int tid  = threadIdx.x;
    const int base = blockIdx.x * 256;
    const int b    = base >> 12;
    const int hw0  = base & 4095;

    #pragma unroll
    for (int j = 0; j < N_CODES / 256; ++j) {
        const int k = tid + j * 256;
        Cs[k] = np_sumsq64_s(cb + k * CODE_DIM, 1);
    }
    float xr[CODE_DIM];
    const float* xin = vec + (size_t)b * 262144 + hw0 + tid;
    #pragma unroll
    for (int c = 0; c < CODE_DIM; ++c) xr[c] = xin[(size_t)c * 4096];
    #pragma unroll
    for (int c = 0; c < CODE_DIM; ++c) asm volatile("" : "+v"(xr[c]));
    const float S = np_sumsq64_s(xr, 1);

    const float4* cb4 = (const float4*)cb;
    #pragma unroll
    for (int j = 0; j < 8; ++j)
        ((float4*)sw[0])[j * 256 + tid] = cb4[j * 256 + tid];
    __syncthreads();

    float m = INFINITY; int mi = 0;
    for (int t = 0; t < NTILES; ++t) {
        const int cur = t & 1;
        float4 g[8];
        if (t + 1 < NTILES) {
            #pragma unroll
            for (int j = 0; j < 8; ++j)
                g[j] = cb4[(size_t)(t + 1) * (KTILE * CODE_DIM / 4) + j * 256 + tid];
        }
        const float* wbase = sw[cur];
        for (int k0 = 0; k0 < KTILE; k0 += 4) {
            const float* w0 = wbase + (size_t)(k0 + 0) * CODE_DIM;
            const float* w1 = wbase + (size_t)(k0 + 1) * CODE_DIM;
            const float* w2 = wbase + (size_t)(k0 + 2) * CODE_DIM;
            const float* w3 = wbase + (size_t)(k0 + 3) * CODE_DIM;
            float d0 = 0.f, d1 = 0.f, d2 = 0.f, d3 = 0.f;
            #pragma unroll
            for (int c4 = 0; c4 < 16; ++c4) {
                const float4 a0 = *(const float4*)(w0 + c4 * 4);
                const float4 a1 = *(const float4*)(w1 + c4 * 4);
                const float4 a2 = *(const float4*)(w2 + c4 * 4);
                const float4 a3 = *(const float4*)(w3 + c4 * 4);
                d0 = __builtin_fmaf(xr[c4*4+0], a0.x, d0); d0 = __builtin_fmaf(xr[c4*4+1], a0.y, d0);
                d0 = __builtin_fmaf(xr[c4*4+2], a0.z, d0); d0 = __builtin_fmaf(xr[c4*4+3], a0.w, d0);
                d1 = __builtin_fmaf(xr[c4*4+0], a1.x, d1); d1 = __builtin_fmaf(xr[c4*4+1], a1.y, d1);
                d1 = __builtin_fmaf(xr[c4*4+2], a1.z, d1); d1 = __builtin_fmaf(xr[c4*4+3], a1.w, d1);
                d2 = __builtin_fmaf(xr[c4*4+0], a2.x, d2); d2 = __builtin_fmaf(xr[c4*4+1], a2.y, d2);
                d2 = __builtin_fmaf(xr[c4*4+2], a2.z, d2); d2 = __builtin_fmaf(xr[c4*4+3], a2.w, d2);
                d3 = __builtin_fmaf(xr[c4*4+0], a3.x, d3); d3 = __builtin_fmaf(xr[c4*4+1], a3.y, d3);
                d3 = __builtin_fmaf(xr[c4*4+2], a3.z, d3); d3 = __builtin_fmaf(xr[c4*4+3], a3.w, d3);
            }
            const int kg = t * KTILE + k0;
            const float4 cv = *(const float4*)&Cs[kg];
            const float t0 = __builtin_fmaf(-2.f, d0, S) + cv.x;
            const float t1 = __builtin_fmaf(-2.f, d1, S) + cv.y;
            const float t2 = __builtin_fmaf(-2.f, d2, S) + cv.z;
            const float t3 = __builtin_fmaf(-2.f, d3, S) + cv.w;
            if (t0 < m) { m = t0; mi = kg;     }
            if (t1 < m) { m = t1; mi = kg + 1; }
            if (t2 < m) { m = t2; mi = kg + 2; }
            if (t3 < m) { m = t3; mi = kg + 3; }
        }
        if (t + 1 < NTILES) {
            #pragma unroll
            for (int j = 0; j < 8; ++j)
                ((float4*)sw[cur ^ 1])[j * 256 + tid] = g[j];
        }
        __syncthreads();
    }
    idxs[tid] = mi;
    __syncthreads();
    const int c4 = (tid & 15) << 2;
    const int r0 = tid >> 4;
    for (int rr = r0; rr < 256; rr += 16) {
        const int wi = idxs[rr];
        const float4 v = *(const float4*)(cb + (size_t)wi * CODE_DIM + c4);
        *(float4*)(out + (size_t)(base + rr) * CODE_DIM + c4) = v;
    }
}

extern "C" void kernel_launch(void* const* d_in, const int* in_sizes, int n_in,
                              void* d_out, int out_size, void* d_ws, size_t ws_size,
                              hipStream_t stream) {
    const float* vec = (const float*)d_in[0];
    const float* cb  = (const float*)d_in[1];
    float* out = (float*)d_out;

    const size_t cbbf_b = (size_t)N_CODES * CODE_DIM * 2;
    const size_t cs_b   = (size_t)N_CODES * 4;
    const size_t need   = cbbf_b + cs_b;
    if (ws_size < need) {
        vq_lds_fallback<<<dim3(ROWS_TOTAL / 256), dim3(256), 0, stream>>>(vec, cb, out);
        return;
    }
    unsigned short* cbbf = (unsigned short*)d_ws;
    float* Csws = (float*)((char*)d_ws + cbbf_b);

    vq_prep<<<dim3(16), dim3(512), 0, stream>>>(cb, cbbf, Csws);
    vq_fused<<<dim3(ROWS_TOTAL / BROWS), dim3(256), 0, stream>>>(vec, cbbf, cb, Csws, out);
}

// Round 17
// 93.711 us; speedup vs baseline: 1.6203x; 1.6203x over previous
//
#include <hip/hip_runtime.h>
#include <math.h>

#define N_CODES     1024
#define CODE_DIM    64
#define ROWS_TOTAL  131072
#define CAND_CAP    12
#define GMARGIN     1e-3f
#define BROWS       128                      // rows per block (4 waves x 32)
#define STAGE_CODES 128
#define STAGE_BYTES (STAGE_CODES * CODE_DIM * 2)   // 16384

typedef float  f32x16  __attribute__((ext_vector_type(16)));
typedef short  short8v __attribute__((ext_vector_type(8)));
typedef __attribute__((address_space(3))) unsigned       lds_u32;
typedef const __attribute__((address_space(1))) unsigned glb_u32;

// ---------- frozen bit-exact pieces (verified rounds 2-16) ----------
__device__ __forceinline__ float np_sumsq64_s(const float* a, int stride) {
#pragma clang fp contract(off)
    float r[8];
    #pragma unroll
    for (int j = 0; j < 8; ++j) r[j] = a[j * stride] * a[j * stride];
    #pragma unroll
    for (int t = 1; t < 8; ++t) {
        #pragma unroll
        for (int j = 0; j < 8; ++j) {
            const float v = a[(t * 8 + j) * stride];
            const float p = v * v;
            r[j] = r[j] + p;
        }
    }
    return ((r[0] + r[1]) + (r[2] + r[3])) + ((r[4] + r[5]) + (r[6] + r[7]));
}

// same tree, reading element c at rq[c ^ x] (XOR-swizzled LDS row copy)
__device__ __forceinline__ float np_sumsq64_lds(const float* rq, int x) {
#pragma clang fp contract(off)
    float r[8];
    #pragma unroll
    for (int j = 0; j < 8; ++j) { const float v = rq[j ^ x]; r[j] = v * v; }
    #pragma unroll
    for (int t = 1; t < 8; ++t) {
        #pragma unroll
        for (int j = 0; j < 8; ++j) {
            const float v = rq[(t * 8 + j) ^ x];
            const float p = v * v;
            r[j] = r[j] + p;
        }
    }
    return ((r[0] + r[1]) + (r[2] + r[3])) + ((r[4] + r[5]) + (r[6] + r[7]));
}

__device__ __forceinline__ unsigned short bf16rne(float f) {
    unsigned int u = __float_as_uint(f);
    return (unsigned short)((u + 0x7FFFu + ((u >> 16) & 1u)) >> 16);
}

__device__ __forceinline__ f32x16 zero16() {
    f32x16 v;
    #pragma unroll
    for (int e = 0; e < 16; ++e) v[e] = 0.f;
    return v;
}

__device__ __forceinline__ float exact_dot_lds(const float* rq, int x,
                                               const float* __restrict__ cb, int k) {
    const float4* wr = (const float4*)(cb + (size_t)k * CODE_DIM);
    float G = 0.f;
    #pragma unroll
    for (int c4 = 0; c4 < 16; ++c4) {
        const float4 wv = wr[c4];
        G = __builtin_fmaf(rq[(c4 * 4 + 0) ^ x], wv.x, G);
        G = __builtin_fmaf(rq[(c4 * 4 + 1) ^ x], wv.y, G);
        G = __builtin_fmaf(rq[(c4 * 4 + 2) ^ x], wv.z, G);
        G = __builtin_fmaf(rq[(c4 * 4 + 3) ^ x], wv.w, G);
    }
    return G;
}

// ordered (T,k) key: smaller key == (smaller T, then smaller k)
__device__ __forceinline__ unsigned long long packTK(float T, int k) {
    unsigned u = __float_as_uint(T);
    unsigned m = (u & 0x80000000u) ? ~u : (u | 0x80000000u);
    return ((unsigned long long)m << 32) | (unsigned)k;
}

// ========== K0: prep — ||w||^2 (numpy tree) + bf16 pre-swizzled codebook ==========
__global__ __launch_bounds__(512) void vq_prep(const float* __restrict__ cb,
                                               unsigned short* __restrict__ cbbf,
                                               float* __restrict__ Csws) {
    const int sid = blockIdx.x * 512 + threadIdx.x;       // 0..8191 (16B slots)
    const float4* cb4 = (const float4*)cb;
    const float4 f0 = cb4[sid * 2 + 0];
    const float4 f1 = cb4[sid * 2 + 1];
    short8v h;
    h[0] = (short)bf16rne(f0.x); h[1] = (short)bf16rne(f0.y);
    h[2] = (short)bf16rne(f0.z); h[3] = (short)bf16rne(f0.w);
    h[4] = (short)bf16rne(f1.x); h[5] = (short)bf16rne(f1.y);
    h[6] = (short)bf16rne(f1.z); h[7] = (short)bf16rne(f1.w);
    const int code = sid >> 3, c8 = sid & 7;
    const int off = (code >> 7) * STAGE_BYTES +
                    (((code & 127) * 128 + c8 * 16) ^ ((code & 7) << 4));
    *(short8v*)((char*)cbbf + off) = h;
    if (sid < N_CODES) Csws[sid] = np_sumsq64_s(cb + sid * CODE_DIM, 1);
}

// ========== K1: FUSED screen (r13, frozen) + COMPACTED rescore tail + gather ======
// 256 threads = 4 waves x 32 rows = 128 rows/block; grid 1024; LDS = 40960 (4/CU).
__global__ __launch_bounds__(256, 4) void vq_fused(
    const float* __restrict__ vec, const unsigned short* __restrict__ cbbf,
    const float* __restrict__ cb, const float* __restrict__ Csws,
    float* __restrict__ out)
{
    __shared__ __align__(16) char pool[2 * STAGE_BYTES];      // cbuf (screen) / rows (tail)
    __shared__ int cnt[BROWS];                                // cnt (screen) / S (tail)
    __shared__ int ks[BROWS * CAND_CAP];                      // 6 KB
    __shared__ unsigned long long res[BROWS];                 // 1 KB
    __shared__ int taskOff[BROWS];                            // 512 B ({q<<16|off} packed)
    // total: 32768 + 512 + 6144 + 1024 + 512 = 40960

    const int tid = threadIdx.x;
    const int l   = tid & 63;
    const int w   = tid >> 6;          // wave 0..3
    const int col = l & 31;
    const int g8  = l >> 5;
    const int rowblk = blockIdx.x * BROWS;

    // ---- A fragment: this lane's row, bf16, pinned in VGPRs ----
    const int r = rowblk + w * 32 + col;
    const float* xb = vec + (size_t)(r >> 12) * 262144 + (r & 4095);
    short8v a[4];
    #pragma unroll
    for (int m = 0; m < 4; ++m) {
        #pragma unroll
        for (int j = 0; j < 8; ++j) {
            const int c = m * 16 + g8 * 8 + j;
            a[m][j] = (short)bf16rne(xb[(size_t)c * 4096]);
        }
    }
    asm volatile("s_waitcnt vmcnt(0)" ::: "memory");
    #pragma unroll
    for (int m = 0; m < 4; ++m) {
        int4 t; __builtin_memcpy(&t, &a[m], 16);
        asm volatile("" : "+v"(t.x), "+v"(t.y), "+v"(t.z), "+v"(t.w));
        __builtin_memcpy(&a[m], &t, 16);
    }

    const char* gsrc = (const char*)cbbf;
    #define STAGE(stg, bufi)                                                        \
        do {                                                                        \
            _Pragma("unroll")                                                       \
            for (int i = 0; i < 4; ++i) {                                           \
                const char* g = gsrc + (stg) * STAGE_BYTES + i * 4096 + tid * 16;   \
                lds_u32* lb = (lds_u32*)(pool + (bufi) * STAGE_BYTES + i * 4096 + (w << 10)); \
                __builtin_amdgcn_global_load_lds((glb_u32*)g, lb, 16, 0, 0);        \
            }                                                                       \
        } while (0)

    f32x16 Um, th;
    #pragma unroll
    for (int e = 0; e < 16; ++e) Um[e] = -INFINITY;

    STAGE(0, 0);
    for (int s = 0; s < 16; ++s) {                     // 2 phases x 8 stages
        const int cur = s & 1;
        if (s < 15) {
            STAGE((s + 1) & 7, cur ^ 1);
            asm volatile("s_waitcnt vmcnt(4)" ::: "memory");
        } else {
            asm volatile("s_waitcnt vmcnt(0)" ::: "memory");
        }
        __builtin_amdgcn_s_barrier();
        __builtin_amdgcn_sched_barrier(0);

        const char* base = pool + cur * STAGE_BYTES;
        const int ph = s >> 3;
        const int kbase = (s & 7) * STAGE_CODES;
        #pragma unroll
        for (int tt = 0; tt < 4; ++tt) {
            const int cl = tt * 32 + col;
            short8v bf[4];
            #pragma unroll
            for (int m = 0; m < 4; ++m) {
                const int off = (cl * 128 + (m * 2 + g8) * 16) ^ ((cl & 7) << 4);
                bf[m] = *(const short8v*)(base + off);
            }
            f32x16 acc = zero16();
            __builtin_amdgcn_s_setprio(1);
            #pragma unroll
            for (int m = 0; m < 4; ++m)
                acc = __builtin_amdgcn_mfma_f32_32x32x16_bf16(a[m], bf[m], acc, 0, 0, 0);
            __builtin_amdgcn_s_setprio(0);

            if (ph == 0) {
                #pragma unroll
                for (int e = 0; e < 16; ++e) Um[e] = fmaxf(Um[e], acc[e]);
            } else {
                const int k = kbase + cl;
                unsigned long long any = 0;
                #pragma unroll
                for (int e = 0; e < 16; ++e) any |= __ballot(acc[e] >= th[e]);
                if (any) {
                    #pragma unroll
                    for (int e = 0; e < 16; ++e) {
                        if (acc[e] >= th[e]) {
                            const int rl = w * 32 + (e & 3) + ((e >> 2) << 3) + (g8 << 2);
                            const int idx = atomicAdd(&cnt[rl], 1);
                            if (idx < CAND_CAP) ks[rl * CAND_CAP + idx] = k;
                        }
                    }
                }
            }
        }

        if (s == 7) {   // transition: butterfly max -> thresholds; zero cnt
            #pragma unroll
            for (int e = 0; e < 16; ++e) {
                float v = Um[e];
                v = fmaxf(v, __shfl_xor(v, 1, 64));
                v = fmaxf(v, __shfl_xor(v, 2, 64));
                v = fmaxf(v, __shfl_xor(v, 4, 64));
                v = fmaxf(v, __shfl_xor(v, 8, 64));
                v = fmaxf(v, __shfl_xor(v, 16, 64));
                th[e] = v - GMARGIN;
            }
            if (l < 32) cnt[w * 32 + l] = 0;           // wave-local rows
        }
        __builtin_amdgcn_s_barrier();
    }
    #undef STAGE

    // ================= tail: COMPACTED exact rescore =================
    __syncthreads();                                   // all waves done with pool

    float (*rows)[CODE_DIM] = (float (*)[CODE_DIM])(pool + (size_t)w * 8192);
    float* Sarr = (float*)cnt;                         // overlay after cnt consumed

    const int c0 = (l < 32) ? cnt[w * 32 + l] : 0;
    if (l < 32) {
        res[w * 32 + l] = ~0ULL;
        if (c0 == 1) res[w * 32 + l] = (unsigned long long)(unsigned)ks[(w * 32 + l) * CAND_CAP];
    }
    // needy rows = cnt>=2 (incl. overflow: they use rows[]/Sarr in coop scan)
    const bool need = (l < 32) && (c0 >= 2);
    const unsigned mask32 = (unsigned)__ballot(need);
    const int nw = __popc(mask32);
    const unsigned long long om0 = __ballot(l < 32 && c0 > CAND_CAP);

    const int tq = (need && c0 <= CAND_CAP) ? c0 : 0;
    int scan = tq;
    #pragma unroll
    for (int off = 1; off < 32; off <<= 1) {
        const int v = __shfl_up(scan, off, 64);
        if (l >= off) scan += v;
    }
    // packed per-compacted-pos entries: {q << 16 | exclusive-offset}; sentinels after
    if (need) {
        const int pos = __popc(mask32 & ((1u << l) - 1u));
        taskOff[w * 32 + pos] = (scan - tq) | (l << 16);
    }
    if (l < 32 && l >= nw) taskOff[w * 32 + l] = 0x7FFF;   // monotone sentinel
    const int total = __shfl(scan, 31, 64);

    // stage ONLY needy rows (compacted): rows[pos][c ^ pos]
    {
        const int pos2 = l & 31, hh = l >> 5;
        if (pos2 < nw) {
            const int q = taskOff[w * 32 + pos2] >> 16;
            const int rr = rowblk + w * 32 + q;
            const float* rb = vec + (size_t)(rr >> 12) * 262144 + (rr & 4095);
            #pragma unroll 4
            for (int i = 0; i < 32; ++i) {
                const int c = i * 2 + hh;
                rows[pos2][c ^ pos2] = rb[(size_t)c * 4096];
            }
        }
    }
    if (l < nw) Sarr[w * 32 + l] = np_sumsq64_lds(rows[l], l);  // numpy tree, by pos

    __syncthreads();

    // ---- task loop: all 64 lanes, one (row,candidate) per lane-round ----
    for (int t = l; t < total; t += 64) {
        int lo = 0, hi = 31;                           // largest pos with off<=t
        #pragma unroll
        for (int it = 0; it < 5; ++it) {
            const int mid = (lo + hi + 1) >> 1;
            if ((taskOff[w * 32 + mid] & 0xFFFF) <= t) lo = mid; else hi = mid - 1;
        }
        const int ent = taskOff[w * 32 + lo];
        const int q   = ent >> 16;
        const int k   = ks[(w * 32 + q) * CAND_CAP + (t - (ent & 0xFFFF))];
        const float S = Sarr[w * 32 + lo];
        const float G = exact_dot_lds(rows[lo], lo, cb, k);
        const float T = __builtin_fmaf(-2.f, G, S) + Csws[k];
        atomicMin(&res[w * 32 + q], packTK(T, k));     // lexicographic (T,k)
    }

    // ---- rare overflow rows: wave-cooperative exact full scan (staged row) ----
    unsigned long long om = om0;
    while (om) {
        const int q = (int)__builtin_ctzll(om); om &= om - 1;
        const int pos = __popc(mask32 & ((1u << q) - 1u));
        const float S = Sarr[w * 32 + pos];
        float bT = INFINITY; int bK = 0x7fffffff;
        #pragma unroll 4
        for (int j = 0; j < 16; ++j) {
            const int k = l * 16 + j;                  // ascending within lane
            const float G = exact_dot_lds(rows[pos], pos, cb, k);
            const float T = __builtin_fmaf(-2.f, G, S) + Csws[k];
            if (T < bT) { bT = T; bK = k; }
        }
        #pragma unroll
        for (int off = 32; off; off >>= 1) {           // lexicographic reduce
            const float oT = __shfl_xor(bT, off, 64);
            const int   oK = __shfl_xor(bK, off, 64);
            if (oT < bT || (oT == bT && oK < bK)) { bT = oT; bK = oK; }
        }
        if (l == 0) res[w * 32 + q] = (unsigned long long)(unsigned)bK;
    }

    __syncthreads();

    // ---- cooperative gather + coalesced float4 output write (128 rows) ----
    const int c4 = (tid & 15) << 2;
    for (int rr = tid >> 4; rr < BROWS; rr += 16) {
        const int wi = (int)(res[rr] & 0xffffffffu);
        const float4 v = *(const float4*)(cb + (size_t)wi * CODE_DIM + c4);
        *(float4*)(out + (size_t)(rowblk + rr) * CODE_DIM + c4) = v;
    }
}

// ================= fallback (round-4 kernel, used if ws too small) =================
#define KTILE 128
#define NTILES (N_CODES / KTILE)
__global__ __launch_bounds__(256, 2) void vq_lds_fallback(
    const float* __restrict__ vec, const float* __restrict__ cb,
    float* __restrict__ out)
{
    __shared__ __align__(16) float sw[2][KTILE * CODE_DIM];
    __shared__ __align__(16) float Cs[N_CODES];
    __shared__ int idxs[256];

    const int tid  = threadIdx.x;
    const int base = blockIdx.x * 256;
    const int b    = base >> 12;
    const int hw0  = base & 4095;

    #pragma unroll
    for (int j = 0; j < N_CODES / 256; ++j) {
        const int k = tid + j * 256;
        Cs[k] = np_sumsq64_s(cb + k * CODE_DIM, 1);
    }
    float xr[CODE_DIM];
    const float* xin = vec + (size_t)b * 262144 + hw0 + tid;
    #pragma unroll
    for (int c = 0; c < CODE_DIM; ++c) xr[c] = xin[(size_t)c * 4096];
    #pragma unroll
    for (int c = 0; c < CODE_DIM; ++c) asm volatile("" : "+v"(xr[c]));
    const float S = np_sumsq64_s(xr, 1);

    const float4* cb4 = (const float4*)cb;
    #pragma unroll
    for (int j = 0; j < 8; ++j)
        ((float4*)sw[0])[j * 256 + tid] = cb4[j * 256 + tid];
    __syncthreads();

    float m = INFINITY; int mi = 0;
    for (int t = 0; t < NTILES; ++t) {
        const int cur = t & 1;
        float4 g[8];
        if (t + 1 < NTILES) {
            #pragma unroll
            for (int j = 0; j < 8; ++j)
                g[j] = cb4[(size_t)(t + 1) * (KTILE * CODE_DIM / 4) + j * 256 + tid];
        }
        const float* wbase = sw[cur];
        for (int k0 = 0; k0 < KTILE; k0 += 4) {
            const float* w0 = wbase + (size_t)(k0 + 0) * CODE_DIM;
            const float* w1 = wbase + (size_t)(k0 + 1) * CODE_DIM;
            const float* w2 = wbase + (size_t)(k0 + 2) * CODE_DIM;
            const float* w3 = wbase + (size_t)(k0 + 3) * CODE_DIM;
            float d0 = 0.f, d1 = 0.f, d2 = 0.f, d3 = 0.f;
            #pragma unroll
            for (int c4 = 0; c4 < 16; ++c4) {
                const float4 a0 = *(const float4*)(w0 + c4 * 4);
                const float4 a1 = *(const float4*)(w1 + c4 * 4);
                const float4 a2 = *(const float4*)(w2 + c4 * 4);
                const float4 a3 = *(const float4*)(w3 + c4 * 4);
                d0 = __builtin_fmaf(xr[c4*4+0], a0.x, d0); d0 = __builtin_fmaf(xr[c4*4+1], a0.y, d0);
                d0 = __builtin_fmaf(xr[c4*4+2], a0.z, d0); d0 = __builtin_fmaf(xr[c4*4+3], a0.w, d0);
                d1 = __builtin_fmaf(xr[c4*4+0], a1.x, d1); d1 = __builtin_fmaf(xr[c4*4+1], a1.y, d1);
                d1 = __builtin_fmaf(xr[c4*4+2], a1.z, d1); d1 = __builtin_fmaf(xr[c4*4+3], a1.w, d1);
                d2 = __builtin_fmaf(xr[c4*4+0], a2.x, d2); d2 = __builtin_fmaf(xr[c4*4+1], a2.y, d2);
                d2 = __builtin_fmaf(xr[c4*4+2], a2.z, d2); d2 = __builtin_fmaf(xr[c4*4+3], a2.w, d2);
                d3 = __builtin_fmaf(xr[c4*4+0], a3.x, d3); d3 = __builtin_fmaf(xr[c4*4+1], a3.y, d3);
                d3 = __builtin_fmaf(xr[c4*4+2], a3.z, d3); d3 = __builtin_fmaf(xr[c4*4+3], a3.w, d3);
            }
            const int kg = t * KTILE + k0;
            const float4 cv = *(const float4*)&Cs[kg];
            const float t0 = __builtin_fmaf(-2.f, d0, S) + cv.x;
            const float t1 = __builtin_fmaf(-2.f, d1, S) + cv.y;
            const float t2 = __builtin_fmaf(-2.f, d2, S) + cv.z;
            const float t3 = __builtin_fmaf(-2.f, d3, S) + cv.w;
            if (t0 < m) { m = t0; mi = kg;     }
            if (t1 < m) { m = t1; mi = kg + 1; }
            if (t2 < m) { m = t2; mi = kg + 2; }
            if (t3 < m) { m = t3; mi = kg + 3; }
        }
        if (t + 1 < NTILES) {
            #pragma unroll
            for (int j = 0; j < 8; ++j)
                ((float4*)sw[cur ^ 1])[j * 256 + tid] = g[j];
        }
        __syncthreads();
    }
    idxs[tid] = mi;
    __syncthreads();
    const int c4 = (tid & 15) << 2;
    const int r0 = tid >> 4;
    for (int rr = r0; rr < 256; rr += 16) {
        const int wi = idxs[rr];
        const float4 v = *(const float4*)(cb + (size_t)wi * CODE_DIM + c4);
        *(float4*)(out + (size_t)(base + rr) * CODE_DIM + c4) = v;
    }
}

extern "C" void kernel_launch(void* const* d_in, const int* in_sizes, int n_in,
                              void* d_out, int out_size, void* d_ws, size_t ws_size,
                              hipStream_t stream) {
    const float* vec = (const float*)d_in[0];
    const float* cb  = (const float*)d_in[1];
    float* out = (float*)d_out;

    const size_t cbbf_b = (size_t)N_CODES * CODE_DIM * 2;
    const size_t cs_b   = (size_t)N_CODES * 4;
    const size_t need   = cbbf_b + cs_b;
    if (ws_size < need) {
        vq_lds_fallback<<<dim3(ROWS_TOTAL / 256), dim3(256), 0, stream>>>(vec, cb, out);
        return;
    }
    unsigned short* cbbf = (unsigned short*)d_ws;
    float* Csws = (float*)((char*)d_ws + cbbf_b);

    vq_prep<<<dim3(16), dim3(512), 0, stream>>>(cb, cbbf, Csws);
    vq_fused<<<dim3(ROWS_TOTAL / BROWS), dim3(256), 0, stream>>>(vec, cbbf, cb, Csws, out);
}